// Round 1
// baseline (395.727 us; speedup 1.0000x reference)
//
#include <hip/hip_runtime.h>

typedef unsigned short u16;
typedef short short8 __attribute__((ext_vector_type(8)));
typedef float f32x4 __attribute__((ext_vector_type(4)));

#define NB 4
#define NS 2048
#define NSTATE 1024
#define NH 16
#define ND 64
#define NM (NB*NS)   // 8192 rows

__device__ __forceinline__ u16 f2bf(float f){
  union { float fv; unsigned uv; } x; x.fv = f;
  unsigned r = x.uv + 0x7fffu + ((x.uv >> 16) & 1u);
  return (u16)(r >> 16);
}

__device__ __forceinline__ f32x4 mfma16x16(short8 a, short8 b, f32x4 c){
  return __builtin_amdgcn_mfma_f32_16x16x32_bf16(a, b, c, 0, 0, 0);
}

__device__ __forceinline__ void gld_lds16(const u16* g, u16* l){
  __builtin_amdgcn_global_load_lds((const __attribute__((address_space(1))) void*)g,
                                   (__attribute__((address_space(3))) void*)l, 16, 0, 0);
}

// ---------------- fp32 -> bf16 conversion for 3 activations + 4 weights ----
__global__ __launch_bounds__(256)
void cvt_all(const float* __restrict__ q, const float* __restrict__ k, const float* __restrict__ v,
             const float* __restrict__ wq, const float* __restrict__ wk,
             const float* __restrict__ wv, const float* __restrict__ wo,
             u16* oq, u16* ok, u16* ov, u16* owq, u16* owk, u16* owv, u16* owo){
  const int XN4 = (NB*NS*NSTATE)/4;   // 2097152
  const int WN4 = (NSTATE*NSTATE)/4;  // 262144
  int gid = blockIdx.x * 256 + threadIdx.x;
  const float* src; u16* dst; int idx;
  if (gid < XN4)          { src = q; dst = oq; idx = gid; }
  else if (gid < 2*XN4)   { src = k; dst = ok; idx = gid - XN4; }
  else if (gid < 3*XN4)   { src = v; dst = ov; idx = gid - 2*XN4; }
  else {
    int g = gid - 3*XN4;
    int wsel = g >> 18;       // / WN4
    idx = g & (WN4 - 1);
    src = (wsel==0)?wq:(wsel==1)?wk:(wsel==2)?wv:wo;
    dst = (wsel==0)?owq:(wsel==1)?owk:(wsel==2)?owv:owo;
  }
  float4 val = ((const float4*)src)[idx];
  ushort4 r;
  r.x = f2bf(val.x); r.y = f2bf(val.y); r.z = f2bf(val.z); r.w = f2bf(val.w);
  ((ushort4*)dst)[idx] = r;
}

// ---------------- GEMM: C[m,n] = sum_k A[m,k] * Bt[n,k]  (M=8192,N=1024,K=1024)
// MODE 0: bf16 out, row-major [M][N]          (V projection)
// MODE 1: qk_scale + RoPE, bf16 out [B,H,S,D] (Q/K projection)
// MODE 2: fp32 out, row-major [M][N]          (final Wo projection)
template<int MODE>
__global__ __launch_bounds__(256)
void gemm_bt(const u16* __restrict__ A, const u16* __restrict__ Bt, void* __restrict__ outp){
  __shared__ __align__(16) u16 As[128*64];
  __shared__ __align__(16) u16 Bs[128*64];
  const int tid = threadIdx.x;
  const int lane = tid & 63, w = tid >> 6;
  const int wr = w >> 1, wc = w & 1;
  const int l15 = lane & 15, lhi = lane >> 4;
  const int brow = blockIdx.y * 128;
  const int bcol = blockIdx.x * 128;
  const int K = NSTATE;
  f32x4 acc[4][4] = {};

  for (int kt = 0; kt < K; kt += 64){
    #pragma unroll
    for (int it = 0; it < 4; ++it){           // stage A tile 128x64
      int flat = it*4096 + tid*16;
      int row = flat >> 7, colb = flat & 127;
      gld_lds16(A + (size_t)(brow+row)*K + kt + (colb>>1), As + (flat>>1));
    }
    #pragma unroll
    for (int it = 0; it < 4; ++it){           // stage B tile 128x64
      int flat = it*4096 + tid*16;
      int row = flat >> 7, colb = flat & 127;
      gld_lds16(Bt + (size_t)(bcol+row)*K + kt + (colb>>1), Bs + (flat>>1));
    }
    __syncthreads();
    #pragma unroll
    for (int ks = 0; ks < 2; ++ks){
      short8 av[4], bv[4];
      #pragma unroll
      for (int i = 0; i < 4; ++i)
        av[i] = *(const short8*)&As[(wr*64 + i*16 + l15)*64 + ks*32 + lhi*8];
      #pragma unroll
      for (int j = 0; j < 4; ++j)
        bv[j] = *(const short8*)&Bs[(wc*64 + j*16 + l15)*64 + ks*32 + lhi*8];
      #pragma unroll
      for (int i = 0; i < 4; ++i)
        #pragma unroll
        for (int j = 0; j < 4; ++j)
          acc[i][j] = mfma16x16(av[i], bv[j], acc[i][j]);
    }
    __syncthreads();
  }

  if (MODE == 0){
    u16* out = (u16*)outp;
    #pragma unroll
    for (int i = 0; i < 4; ++i)
      #pragma unroll
      for (int reg = 0; reg < 4; ++reg){
        int m = brow + wr*64 + i*16 + lhi*4 + reg;
        u16* orow = out + (size_t)m*NSTATE + bcol + wc*64;
        #pragma unroll
        for (int j = 0; j < 4; ++j)
          orow[j*16 + l15] = f2bf(acc[i][j][reg]);
      }
  } else if (MODE == 2){
    float* out = (float*)outp;
    #pragma unroll
    for (int i = 0; i < 4; ++i)
      #pragma unroll
      for (int reg = 0; reg < 4; ++reg){
        int m = brow + wr*64 + i*16 + lhi*4 + reg;
        float* orow = out + (size_t)m*NSTATE + bcol + wc*64;
        #pragma unroll
        for (int j = 0; j < 4; ++j)
          orow[j*16 + l15] = acc[i][j][reg];
      }
  } else {
    // MODE 1: scale + RoPE on d<32, write [B,H,S,D]
    u16* out = (u16*)outp;
    const float qk_scale = 0.35355339059327373f;   // (1/sqrt(64))^0.5
    const int head = (bcol + wc*64) >> 6;          // wave covers exactly one head (64 cols)
    const float invf = __powf(10000.0f, -(float)l15 * (1.0f/16.0f));
    #pragma unroll
    for (int i = 0; i < 4; ++i){
      #pragma unroll
      for (int reg = 0; reg < 4; ++reg){
        int m = brow + wr*64 + i*16 + lhi*4 + reg;
        int b = m >> 11, s = m & (NS-1);
        float sn, cs;
        __sincosf((float)s * invf, &sn, &cs);
        float x0 = acc[i][0][reg]*qk_scale;   // d = l15      (first rope half)
        float x1 = acc[i][1][reg]*qk_scale;   // d = 16+l15   (second rope half)
        u16* orow = out + ((size_t)(b*NH + head)*NS + s)*ND;
        orow[ 0 + l15] = f2bf(x0*cs - x1*sn);
        orow[16 + l15] = f2bf(x1*cs + x0*sn);
        orow[32 + l15] = f2bf(acc[i][2][reg]*qk_scale);
        orow[48 + l15] = f2bf(acc[i][3][reg]*qk_scale);
      }
    }
  }
}

// ---------------- V [B,S,H,D] -> Vt [B,H,D,S] ----------------
__global__ __launch_bounds__(256)
void transpose_v(const u16* __restrict__ Vsd, u16* __restrict__ Vt){
  __shared__ u16 tile[64][65];
  const int bh = blockIdx.y, b = bh >> 4, h = bh & 15;
  const int s0 = blockIdx.x * 64;
  const int tid = threadIdx.x;
  #pragma unroll
  for (int p = 0; p < 2; ++p){
    int r = p*32 + (tid>>3);
    int c = (tid&7)*8;
    const u16* g = Vsd + ((size_t)((b*NS + s0 + r)*NH + h))*ND + c;
    ushort4 v0 = *(const ushort4*)g;
    ushort4 v1 = *(const ushort4*)(g+4);
    tile[r][c+0]=v0.x; tile[r][c+1]=v0.y; tile[r][c+2]=v0.z; tile[r][c+3]=v0.w;
    tile[r][c+4]=v1.x; tile[r][c+5]=v1.y; tile[r][c+6]=v1.z; tile[r][c+7]=v1.w;
  }
  __syncthreads();
  #pragma unroll
  for (int p = 0; p < 2; ++p){
    int d  = p*32 + (tid>>3);
    int sc = (tid&7)*8;
    union { u16 u[8]; uint4 v; } o;
    #pragma unroll
    for (int i = 0; i < 8; ++i) o.u[i] = tile[sc+i][d];
    *(uint4*)(Vt + ((size_t)(bh*ND + d))*NS + s0 + sc) = o.v;
  }
}

// ---------------- causal flash attention -----------------------------------
// grid (S/128, B*H), 4 waves/block, each wave owns 32 q rows independently.
__global__ __launch_bounds__(256)
void flash_attn(const u16* __restrict__ Q, const u16* __restrict__ Kh,
                const u16* __restrict__ Vt, u16* __restrict__ O){
  __shared__ __align__(16) u16 Plds[4][32*64];
  const int bh = blockIdx.y;
  const int q0 = blockIdx.x * 128;
  const int tid = threadIdx.x;
  const int w = tid >> 6, lane = tid & 63;
  const int l15 = lane & 15, lhi = lane >> 4;
  const int qw = q0 + w*32;
  const u16* Qb = Q  + (size_t)bh*NS*ND;
  const u16* Kb = Kh + (size_t)bh*NS*ND;
  const u16* Vb = Vt + (size_t)bh*ND*NS;
  u16* Pl = &Plds[w][0];

  short8 qf[2][2];
  #pragma unroll
  for (int rf = 0; rf < 2; ++rf)
    #pragma unroll
    for (int ks = 0; ks < 2; ++ks)
      qf[rf][ks] = *(const short8*)&Qb[(size_t)(qw + rf*16 + l15)*ND + ks*32 + lhi*8];

  f32x4 oacc[2][4] = {};
  float mrow[2][4], lrow[2][4];
  #pragma unroll
  for (int rf = 0; rf < 2; ++rf)
    #pragma unroll
    for (int r = 0; r < 4; ++r){ mrow[rf][r] = -3.0e38f; lrow[rf][r] = 0.f; }

  const int kend = qw + 32;
  for (int kv0 = 0; kv0 < kend; kv0 += 64){
    // ---- S = q . k^T  (scale already folded into q,k) ----
    f32x4 sacc[2][4] = {};
    #pragma unroll
    for (int ks = 0; ks < 2; ++ks){
      short8 kf[4];
      #pragma unroll
      for (int cf = 0; cf < 4; ++cf)
        kf[cf] = *(const short8*)&Kb[(size_t)(kv0 + cf*16 + l15)*ND + ks*32 + lhi*8];
      #pragma unroll
      for (int rf = 0; rf < 2; ++rf)
        #pragma unroll
        for (int cf = 0; cf < 4; ++cf)
          sacc[rf][cf] = mfma16x16(qf[rf][ks], kf[cf], sacc[rf][cf]);
    }
    // ---- causal mask ----
    if (kv0 + 63 > qw){
      #pragma unroll
      for (int rf = 0; rf < 2; ++rf)
        #pragma unroll
        for (int cf = 0; cf < 4; ++cf){
          int kvc = kv0 + cf*16 + l15;
          int qbase = qw + rf*16 + lhi*4;
          #pragma unroll
          for (int reg = 0; reg < 4; ++reg)
            if (kvc > qbase + reg) sacc[rf][cf][reg] = -3.0e30f;
        }
    }
    // ---- online softmax ----
    #pragma unroll
    for (int rf = 0; rf < 2; ++rf){
      float al[4];
      #pragma unroll
      for (int reg = 0; reg < 4; ++reg){
        float t = fmaxf(fmaxf(sacc[rf][0][reg], sacc[rf][1][reg]),
                        fmaxf(sacc[rf][2][reg], sacc[rf][3][reg]));
        for (int off = 1; off < 16; off <<= 1) t = fmaxf(t, __shfl_xor(t, off));
        float mnew = fmaxf(mrow[rf][reg], t);
        float alpha = __expf(mrow[rf][reg] - mnew);
        mrow[rf][reg] = mnew;
        float rs = 0.f;
        #pragma unroll
        for (int cf = 0; cf < 4; ++cf){
          float p = __expf(sacc[rf][cf][reg] - mnew);
          sacc[rf][cf][reg] = p;
          rs += p;
        }
        for (int off = 1; off < 16; off <<= 1) rs += __shfl_xor(rs, off);
        lrow[rf][reg] = lrow[rf][reg]*alpha + rs;
        al[reg] = alpha;
      }
      #pragma unroll
      for (int df = 0; df < 4; ++df)
        #pragma unroll
        for (int reg = 0; reg < 4; ++reg)
          oacc[rf][df][reg] *= al[reg];
    }
    // ---- P -> LDS (bf16, XOR-swizzled rows) ----
    #pragma unroll
    for (int rf = 0; rf < 2; ++rf)
      #pragma unroll
      for (int cf = 0; cf < 4; ++cf)
        #pragma unroll
        for (int reg = 0; reg < 4; ++reg){
          int row = rf*16 + lhi*4 + reg;
          int col = cf*16 + l15;
          int bo = ((row<<7) + (col<<1)) ^ ((row&7)<<4);
          *(u16*)((char*)Pl + bo) = f2bf(sacc[rf][cf][reg]);
        }
    asm volatile("s_waitcnt lgkmcnt(0)" ::: "memory");
    // ---- O += P . V ----
    #pragma unroll
    for (int ks = 0; ks < 2; ++ks){
      short8 pf[2], vf[4];
      #pragma unroll
      for (int rf = 0; rf < 2; ++rf){
        int row = rf*16 + l15;
        int bo = ((row<<7) + ((ks*32 + lhi*8)<<1)) ^ ((row&7)<<4);
        pf[rf] = *(const short8*)((const char*)Pl + bo);
      }
      #pragma unroll
      for (int df = 0; df < 4; ++df)
        vf[df] = *(const short8*)&Vb[(size_t)(df*16 + l15)*NS + kv0 + ks*32 + lhi*8];
      #pragma unroll
      for (int rf = 0; rf < 2; ++rf)
        #pragma unroll
        for (int df = 0; df < 4; ++df)
          oacc[rf][df] = mfma16x16(pf[rf], vf[df], oacc[rf][df]);
    }
  }
  // ---- epilogue: O/l -> [B,S,H*D] bf16 ----
  const int b = bh >> 4, h = bh & 15;
  #pragma unroll
  for (int rf = 0; rf < 2; ++rf)
    #pragma unroll
    for (int reg = 0; reg < 4; ++reg){
      float inv = 1.0f / lrow[rf][reg];
      int qrow = qw + rf*16 + lhi*4 + reg;
      u16* orow = O + ((size_t)(b*NS + qrow))*NSTATE + h*ND;
      #pragma unroll
      for (int df = 0; df < 4; ++df)
        orow[df*16 + l15] = f2bf(oacc[rf][df][reg] * inv);
    }
}

// ---------------------------------------------------------------------------
extern "C" void kernel_launch(void* const* d_in, const int* in_sizes, int n_in,
                              void* d_out, int out_size, void* d_ws, size_t ws_size,
                              hipStream_t stream){
  const float* q_src = (const float*)d_in[0];
  const float* k_src = (const float*)d_in[1];
  const float* v_src = (const float*)d_in[2];
  // d_in[3] = position_mask (causal, statically known) — unused
  const float* Wq = (const float*)d_in[4];
  const float* Wk = (const float*)d_in[5];
  const float* Wv = (const float*)d_in[6];
  const float* Wo = (const float*)d_in[7];

  char* ws = (char*)d_ws;
  const size_t MB = 1u << 20;
  if (ws_size < 104*MB) return;   // need 104 MB of scratch

  u16* xq   = (u16*)(ws +  0*MB);   // 16 MB  (bf16 q_src)   -> reused as Vt
  u16* xk   = (u16*)(ws + 16*MB);   // 16 MB  (bf16 k_src)   -> reused as attn out
  u16* xv   = (u16*)(ws + 32*MB);   // 16 MB  (bf16 v_src)
  u16* wq16 = (u16*)(ws + 48*MB);   //  2 MB
  u16* wk16 = (u16*)(ws + 50*MB);
  u16* wv16 = (u16*)(ws + 52*MB);
  u16* wo16 = (u16*)(ws + 54*MB);
  u16* Qh   = (u16*)(ws + 56*MB);   // 16 MB  [B,H,S,D]
  u16* Kk   = (u16*)(ws + 72*MB);   // 16 MB  [B,H,S,D]
  u16* Vsd  = (u16*)(ws + 88*MB);   // 16 MB  [B,S,H,D]
  u16* Vt   = xq;                   // [B,H,D,S]  (xq dead after Q gemm)
  u16* Oat  = xk;                   // [B,S,H*D]  (xk dead after K gemm)

  cvt_all<<<dim3(28672), dim3(256), 0, stream>>>(q_src, k_src, v_src, Wq, Wk, Wv, Wo,
                                                 xq, xk, xv, wq16, wk16, wv16, wo16);
  gemm_bt<1><<<dim3(8,64), dim3(256), 0, stream>>>(xq, wq16, (void*)Qh);
  gemm_bt<1><<<dim3(8,64), dim3(256), 0, stream>>>(xk, wk16, (void*)Kk);
  gemm_bt<0><<<dim3(8,64), dim3(256), 0, stream>>>(xv, wv16, (void*)Vsd);
  transpose_v<<<dim3(32,64), dim3(256), 0, stream>>>(Vsd, Vt);
  flash_attn<<<dim3(16,64), dim3(256), 0, stream>>>(Qh, Kk, Vt, Oat);
  gemm_bt<2><<<dim3(8,64), dim3(256), 0, stream>>>(Oat, wo16, d_out);
}

// Round 2
// 321.977 us; speedup vs baseline: 1.2291x; 1.2291x over previous
//
#include <hip/hip_runtime.h>

typedef unsigned short u16;
typedef unsigned int u32;
typedef short short8 __attribute__((ext_vector_type(8)));
typedef float f32x4 __attribute__((ext_vector_type(4)));

#define NB 4
#define NS 2048
#define NSTATE 1024
#define NH 16
#define ND 64
#define NM (NB*NS)   // 8192 rows

__device__ __forceinline__ u16 f2bf(float f){
  union { float fv; unsigned uv; } x; x.fv = f;
  unsigned r = x.uv + 0x7fffu + ((x.uv >> 16) & 1u);
  return (u16)(r >> 16);
}

__device__ __forceinline__ u32 cvtpk(float lo, float hi){
  u32 r;
  asm("v_cvt_pk_bf16_f32 %0, %1, %2" : "=v"(r) : "v"(lo), "v"(hi));
  return r;
}

__device__ __forceinline__ f32x4 mfma16x16(short8 a, short8 b, f32x4 c){
  return __builtin_amdgcn_mfma_f32_16x16x32_bf16(a, b, c, 0, 0, 0);
}

__device__ __forceinline__ void gld_lds16(const u16* g, u16* l){
  __builtin_amdgcn_global_load_lds((const __attribute__((address_space(1))) void*)g,
                                   (__attribute__((address_space(3))) void*)l, 16, 0, 0);
}

// ---------------- fp32 -> bf16 conversion for 3 activations + 4 weights ----
__global__ __launch_bounds__(256)
void cvt_all(const float* __restrict__ q, const float* __restrict__ k, const float* __restrict__ v,
             const float* __restrict__ wq, const float* __restrict__ wk,
             const float* __restrict__ wv, const float* __restrict__ wo,
             u16* oq, u16* ok, u16* ov, u16* owq, u16* owk, u16* owv, u16* owo){
  const int XN4 = (NB*NS*NSTATE)/4;   // 2097152
  const int WN4 = (NSTATE*NSTATE)/4;  // 262144
  int gid = blockIdx.x * 256 + threadIdx.x;
  const float* src; u16* dst; int idx;
  if (gid < XN4)          { src = q; dst = oq; idx = gid; }
  else if (gid < 2*XN4)   { src = k; dst = ok; idx = gid - XN4; }
  else if (gid < 3*XN4)   { src = v; dst = ov; idx = gid - 2*XN4; }
  else {
    int g = gid - 3*XN4;
    int wsel = g >> 18;       // / WN4
    idx = g & (WN4 - 1);
    src = (wsel==0)?wq:(wsel==1)?wk:(wsel==2)?wv:wo;
    dst = (wsel==0)?owq:(wsel==1)?owk:(wsel==2)?owv:owo;
  }
  float4 val = ((const float4*)src)[idx];
  ushort4 r;
  r.x = f2bf(val.x); r.y = f2bf(val.y); r.z = f2bf(val.z); r.w = f2bf(val.w);
  ((ushort4*)dst)[idx] = r;
}

// ---------------- GEMM: C[m,n] = sum_k A[m,k] * Bt[n,k]  (M=8192,N=1024,K=1024)
// MODE 0: bf16 out, row-major [M][N]          (V projection)
// MODE 1: qk_scale + RoPE, bf16 out [B,H,S,D] (Q/K projection)
// MODE 2: fp32 out, row-major [M][N]          (final Wo projection)
template<int MODE>
__global__ __launch_bounds__(256)
void gemm_bt(const u16* __restrict__ A, const u16* __restrict__ Bt, void* __restrict__ outp){
  __shared__ __align__(16) u16 As[128*64];
  __shared__ __align__(16) u16 Bs[128*64];
  const int tid = threadIdx.x;
  const int lane = tid & 63, w = tid >> 6;
  const int wr = w >> 1, wc = w & 1;
  const int l15 = lane & 15, lhi = lane >> 4;
  const int brow = blockIdx.y * 128;
  const int bcol = blockIdx.x * 128;
  const int K = NSTATE;
  f32x4 acc[4][4] = {};

  for (int kt = 0; kt < K; kt += 64){
    #pragma unroll
    for (int it = 0; it < 4; ++it){           // stage A tile 128x64
      int flat = it*4096 + tid*16;
      int row = flat >> 7, colb = flat & 127;
      gld_lds16(A + (size_t)(brow+row)*K + kt + (colb>>1), As + (flat>>1));
    }
    #pragma unroll
    for (int it = 0; it < 4; ++it){           // stage B tile 128x64
      int flat = it*4096 + tid*16;
      int row = flat >> 7, colb = flat & 127;
      gld_lds16(Bt + (size_t)(bcol+row)*K + kt + (colb>>1), Bs + (flat>>1));
    }
    __syncthreads();
    #pragma unroll
    for (int ks = 0; ks < 2; ++ks){
      short8 av[4], bv[4];
      #pragma unroll
      for (int i = 0; i < 4; ++i)
        av[i] = *(const short8*)&As[(wr*64 + i*16 + l15)*64 + ks*32 + lhi*8];
      #pragma unroll
      for (int j = 0; j < 4; ++j)
        bv[j] = *(const short8*)&Bs[(wc*64 + j*16 + l15)*64 + ks*32 + lhi*8];
      #pragma unroll
      for (int i = 0; i < 4; ++i)
        #pragma unroll
        for (int j = 0; j < 4; ++j)
          acc[i][j] = mfma16x16(av[i], bv[j], acc[i][j]);
    }
    __syncthreads();
  }

  if (MODE == 0){
    u16* out = (u16*)outp;
    #pragma unroll
    for (int i = 0; i < 4; ++i)
      #pragma unroll
      for (int reg = 0; reg < 4; ++reg){
        int m = brow + wr*64 + i*16 + lhi*4 + reg;
        u16* orow = out + (size_t)m*NSTATE + bcol + wc*64;
        #pragma unroll
        for (int j = 0; j < 4; ++j)
          orow[j*16 + l15] = f2bf(acc[i][j][reg]);
      }
  } else if (MODE == 2){
    float* out = (float*)outp;
    #pragma unroll
    for (int i = 0; i < 4; ++i)
      #pragma unroll
      for (int reg = 0; reg < 4; ++reg){
        int m = brow + wr*64 + i*16 + lhi*4 + reg;
        float* orow = out + (size_t)m*NSTATE + bcol + wc*64;
        #pragma unroll
        for (int j = 0; j < 4; ++j)
          orow[j*16 + l15] = acc[i][j][reg];
      }
  } else {
    // MODE 1: scale + RoPE on d<32, write [B,H,S,D]
    u16* out = (u16*)outp;
    const float qk_scale = 0.35355339059327373f;   // (1/sqrt(64))^0.5
    const int head = (bcol + wc*64) >> 6;          // wave covers exactly one head (64 cols)
    const float invf = __powf(10000.0f, -(float)l15 * (1.0f/16.0f));
    #pragma unroll
    for (int i = 0; i < 4; ++i){
      #pragma unroll
      for (int reg = 0; reg < 4; ++reg){
        int m = brow + wr*64 + i*16 + lhi*4 + reg;
        int b = m >> 11, s = m & (NS-1);
        float sn, cs;
        __sincosf((float)s * invf, &sn, &cs);
        float x0 = acc[i][0][reg]*qk_scale;   // d = l15      (first rope half)
        float x1 = acc[i][1][reg]*qk_scale;   // d = 16+l15   (second rope half)
        u16* orow = out + ((size_t)(b*NH + head)*NS + s)*ND;
        orow[ 0 + l15] = f2bf(x0*cs - x1*sn);
        orow[16 + l15] = f2bf(x1*cs + x0*sn);
        orow[32 + l15] = f2bf(acc[i][2][reg]*qk_scale);
        orow[48 + l15] = f2bf(acc[i][3][reg]*qk_scale);
      }
    }
  }
}

// ---------------- V [B,S,H,D] -> Vt [B,H,D,S] ----------------
__global__ __launch_bounds__(256)
void transpose_v(const u16* __restrict__ Vsd, u16* __restrict__ Vt){
  __shared__ u16 tile[64][65];
  const int bh = blockIdx.y, b = bh >> 4, h = bh & 15;
  const int s0 = blockIdx.x * 64;
  const int tid = threadIdx.x;
  #pragma unroll
  for (int p = 0; p < 2; ++p){
    int r = p*32 + (tid>>3);
    int c = (tid&7)*8;
    const u16* g = Vsd + ((size_t)((b*NS + s0 + r)*NH + h))*ND + c;
    ushort4 v0 = *(const ushort4*)g;
    ushort4 v1 = *(const ushort4*)(g+4);
    tile[r][c+0]=v0.x; tile[r][c+1]=v0.y; tile[r][c+2]=v0.z; tile[r][c+3]=v0.w;
    tile[r][c+4]=v1.x; tile[r][c+5]=v1.y; tile[r][c+6]=v1.z; tile[r][c+7]=v1.w;
  }
  __syncthreads();
  #pragma unroll
  for (int p = 0; p < 2; ++p){
    int d  = p*32 + (tid>>3);
    int sc = (tid&7)*8;
    union { u16 u[8]; uint4 v; } o;
    #pragma unroll
    for (int i = 0; i < 8; ++i) o.u[i] = tile[sc+i][d];
    *(uint4*)(Vt + ((size_t)(bh*ND + d))*NS + s0 + sc) = o.v;
  }
}

// ---------------- causal flash attention -----------------------------------
// grid (16, B*H), 4 waves/block. Complementary chunk pairing: waves 0,1 work
// q-chunk blockIdx.x, waves 2,3 work chunk 31-blockIdx.x -> every block does
// exactly 66 wave-iterations (perfect balance).
// Swapped QK^T: st = mfma(K, Q) so each lane owns one q-column with 16
// lane-local k-values -> in-lane softmax trees + 2 shfl_xor; P packed with
// v_cvt_pk_bf16_f32 and stored as ds_write_b64 (XOR-swizzled both sides).
__global__ __launch_bounds__(256)
void flash_attn(const u16* __restrict__ Q, const u16* __restrict__ Kh,
                const u16* __restrict__ Vt, u16* __restrict__ O){
  __shared__ __align__(16) u16 Plds[4][32*64];
  const int bh = blockIdx.y;
  const int tid = threadIdx.x;
  const int w = tid >> 6, lane = tid & 63;
  const int l15 = lane & 15, lhi = lane >> 4;
  const int chunk = (w < 2) ? blockIdx.x : (31 - blockIdx.x);
  const int qw = chunk*64 + (w & 1)*32;
  const u16* Qb = Q  + (size_t)bh*NS*ND;
  const u16* Kb = Kh + (size_t)bh*NS*ND;
  const u16* Vb = Vt + (size_t)bh*ND*NS;
  u16* Pl = &Plds[w][0];

  short8 qf[2][2];
  #pragma unroll
  for (int rf = 0; rf < 2; ++rf)
    #pragma unroll
    for (int ks = 0; ks < 2; ++ks)
      qf[rf][ks] = *(const short8*)&Qb[(size_t)(qw + rf*16 + l15)*ND + ks*32 + lhi*8];

  f32x4 oacc[2][4] = {};
  float mrun[2] = {-3.0e38f, -3.0e38f};
  float lrun[2] = {0.f, 0.f};

  const int kend = qw + 32;
  for (int kv0 = 0; kv0 < kend; kv0 += 64){
    // ---- S^T = K . Q^T : st[rf][cf] rows=k (lhi*4+reg), cols=q (l15) ----
    f32x4 st[2][4] = {};
    #pragma unroll
    for (int ks = 0; ks < 2; ++ks){
      short8 kf[4];
      #pragma unroll
      for (int cf = 0; cf < 4; ++cf)
        kf[cf] = *(const short8*)&Kb[(size_t)(kv0 + cf*16 + l15)*ND + ks*32 + lhi*8];
      #pragma unroll
      for (int rf = 0; rf < 2; ++rf)
        #pragma unroll
        for (int cf = 0; cf < 4; ++cf)
          st[rf][cf] = mfma16x16(kf[cf], qf[rf][ks], st[rf][cf]);
    }
    // ---- causal mask: element (k = kv0+cf*16+lhi*4+reg, q = qw+rf*16+l15) ----
    if (kv0 + 63 > qw){
      #pragma unroll
      for (int rf = 0; rf < 2; ++rf){
        int qq = qw + rf*16 + l15;
        #pragma unroll
        for (int cf = 0; cf < 4; ++cf){
          int kb = kv0 + cf*16 + lhi*4;
          #pragma unroll
          for (int reg = 0; reg < 4; ++reg)
            if (kb + reg > qq) st[rf][cf][reg] = -3.0e30f;
        }
      }
    }
    // ---- per-q-row max: in-lane tree over 16 + shfl_xor(16,32) ----
    float pmax[2];
    #pragma unroll
    for (int rf = 0; rf < 2; ++rf){
      float c4[4];
      #pragma unroll
      for (int cf = 0; cf < 4; ++cf)
        c4[cf] = fmaxf(fmaxf(st[rf][cf][0], st[rf][cf][1]),
                       fmaxf(st[rf][cf][2], st[rf][cf][3]));
      float t = fmaxf(fmaxf(c4[0], c4[1]), fmaxf(c4[2], c4[3]));
      t = fmaxf(t, __shfl_xor(t, 16));
      t = fmaxf(t, __shfl_xor(t, 32));
      pmax[rf] = t;
    }
    // ---- defer-max (T13): rescale only when max grows by > 8 ----
    bool need = (pmax[0] > mrun[0] + 8.f) || (pmax[1] > mrun[1] + 8.f);
    if (__any(need)){
      #pragma unroll
      for (int rf = 0; rf < 2; ++rf){
        float mn = fmaxf(mrun[rf], pmax[rf]);
        float a  = __expf(mrun[rf] - mn);
        mrun[rf] = mn;
        lrun[rf] *= a;
        #pragma unroll
        for (int reg = 0; reg < 4; ++reg){
          float aT = __shfl(a, lhi*4 + reg, 64);   // alpha for q-row lhi*4+reg
          #pragma unroll
          for (int df = 0; df < 4; ++df)
            oacc[rf][df][reg] *= aT;
        }
      }
    }
    // ---- P = exp(S - m), row-sum, pack & store to LDS ----
    #pragma unroll
    for (int rf = 0; rf < 2; ++rf){
      #pragma unroll
      for (int cf = 0; cf < 4; ++cf)
        #pragma unroll
        for (int reg = 0; reg < 4; ++reg)
          st[rf][cf][reg] = __expf(st[rf][cf][reg] - mrun[rf]);
      float s4[4];
      #pragma unroll
      for (int cf = 0; cf < 4; ++cf)
        s4[cf] = (st[rf][cf][0] + st[rf][cf][1]) + (st[rf][cf][2] + st[rf][cf][3]);
      float rs = (s4[0] + s4[1]) + (s4[2] + s4[3]);
      rs += __shfl_xor(rs, 16);
      rs += __shfl_xor(rs, 32);
      lrun[rf] += rs;
      int row = rf*16 + l15;
      #pragma unroll
      for (int cf = 0; cf < 4; ++cf){
        uint2 pk;
        pk.x = cvtpk(st[rf][cf][0], st[rf][cf][1]);
        pk.y = cvtpk(st[rf][cf][2], st[rf][cf][3]);
        int bo = ((row<<7) + ((cf*16 + lhi*4)<<1)) ^ ((row&7)<<4);
        *(uint2*)((char*)Pl + bo) = pk;
      }
    }
    // ---- O += P . V ----
    #pragma unroll
    for (int ks = 0; ks < 2; ++ks){
      short8 pf[2], vf[4];
      #pragma unroll
      for (int rf = 0; rf < 2; ++rf){
        int row = rf*16 + l15;
        int bo = ((row<<7) + ((ks*32 + lhi*8)<<1)) ^ ((row&7)<<4);
        pf[rf] = *(const short8*)((const char*)Pl + bo);
      }
      #pragma unroll
      for (int df = 0; df < 4; ++df)
        vf[df] = *(const short8*)&Vb[(size_t)(df*16 + l15)*NS + kv0 + ks*32 + lhi*8];
      #pragma unroll
      for (int rf = 0; rf < 2; ++rf)
        #pragma unroll
        for (int df = 0; df < 4; ++df)
          oacc[rf][df] = mfma16x16(pf[rf], vf[df], oacc[rf][df]);
    }
  }
  // ---- epilogue: O/l -> [B,S,H*D] bf16 ----
  const int b = bh >> 4, h = bh & 15;
  #pragma unroll
  for (int rf = 0; rf < 2; ++rf){
    float inv = 1.0f / lrun[rf];
    #pragma unroll
    for (int reg = 0; reg < 4; ++reg){
      float invT = __shfl(inv, lhi*4 + reg, 64);
      int qrow = qw + rf*16 + lhi*4 + reg;
      u16* orow = O + ((size_t)(b*NS + qrow))*NSTATE + h*ND;
      #pragma unroll
      for (int df = 0; df < 4; ++df)
        orow[df*16 + l15] = f2bf(oacc[rf][df][reg] * invT);
    }
  }
}

// ---------------------------------------------------------------------------
extern "C" void kernel_launch(void* const* d_in, const int* in_sizes, int n_in,
                              void* d_out, int out_size, void* d_ws, size_t ws_size,
                              hipStream_t stream){
  const float* q_src = (const float*)d_in[0];
  const float* k_src = (const float*)d_in[1];
  const float* v_src = (const float*)d_in[2];
  // d_in[3] = position_mask (causal, statically known) — unused
  const float* Wq = (const float*)d_in[4];
  const float* Wk = (const float*)d_in[5];
  const float* Wv = (const float*)d_in[6];
  const float* Wo = (const float*)d_in[7];

  char* ws = (char*)d_ws;
  const size_t MB = 1u << 20;
  if (ws_size < 104*MB) return;   // need 104 MB of scratch

  u16* xq   = (u16*)(ws +  0*MB);   // 16 MB  (bf16 q_src)   -> reused as Vt
  u16* xk   = (u16*)(ws + 16*MB);   // 16 MB  (bf16 k_src)   -> reused as attn out
  u16* xv   = (u16*)(ws + 32*MB);   // 16 MB  (bf16 v_src)
  u16* wq16 = (u16*)(ws + 48*MB);   //  2 MB
  u16* wk16 = (u16*)(ws + 50*MB);
  u16* wv16 = (u16*)(ws + 52*MB);
  u16* wo16 = (u16*)(ws + 54*MB);
  u16* Qh   = (u16*)(ws + 56*MB);   // 16 MB  [B,H,S,D]
  u16* Kk   = (u16*)(ws + 72*MB);   // 16 MB  [B,H,S,D]
  u16* Vsd  = (u16*)(ws + 88*MB);   // 16 MB  [B,S,H,D]
  u16* Vt   = xq;                   // [B,H,D,S]  (xq dead after Q gemm)
  u16* Oat  = xk;                   // [B,S,H*D]  (xk dead after K gemm)

  cvt_all<<<dim3(28672), dim3(256), 0, stream>>>(q_src, k_src, v_src, Wq, Wk, Wv, Wo,
                                                 xq, xk, xv, wq16, wk16, wv16, wo16);
  gemm_bt<1><<<dim3(8,64), dim3(256), 0, stream>>>(xq, wq16, (void*)Qh);
  gemm_bt<1><<<dim3(8,64), dim3(256), 0, stream>>>(xk, wk16, (void*)Kk);
  gemm_bt<0><<<dim3(8,64), dim3(256), 0, stream>>>(xv, wv16, (void*)Vsd);
  transpose_v<<<dim3(32,64), dim3(256), 0, stream>>>(Vsd, Vt);
  flash_attn<<<dim3(16,64), dim3(256), 0, stream>>>(Qh, Kk, Vt, Oat);
  gemm_bt<2><<<dim3(8,64), dim3(256), 0, stream>>>(Oat, wo16, d_out);
}

// Round 3
// 306.113 us; speedup vs baseline: 1.2927x; 1.0518x over previous
//
#include <hip/hip_runtime.h>

typedef unsigned short u16;
typedef unsigned int u32;
typedef short short8 __attribute__((ext_vector_type(8)));
typedef float f32x4 __attribute__((ext_vector_type(4)));

#define NB 4
#define NS 2048
#define NSTATE 1024
#define NH 16
#define ND 64
#define NM (NB*NS)   // 8192 rows

#if __has_builtin(__builtin_amdgcn_exp2f)
#define EXP2(x) __builtin_amdgcn_exp2f(x)
#else
#define EXP2(x) __expf((x) * 0.6931471805599453f)
#endif

__device__ __forceinline__ u16 f2bf(float f){
  union { float fv; unsigned uv; } x; x.fv = f;
  unsigned r = x.uv + 0x7fffu + ((x.uv >> 16) & 1u);
  return (u16)(r >> 16);
}

__device__ __forceinline__ u32 cvtpk(float lo, float hi){
  u32 r;
  asm("v_cvt_pk_bf16_f32 %0, %1, %2" : "=v"(r) : "v"(lo), "v"(hi));
  return r;
}

__device__ __forceinline__ f32x4 mfma16x16(short8 a, short8 b, f32x4 c){
  return __builtin_amdgcn_mfma_f32_16x16x32_bf16(a, b, c, 0, 0, 0);
}

__device__ __forceinline__ void gld_lds16(const u16* g, u16* l){
  __builtin_amdgcn_global_load_lds((const __attribute__((address_space(1))) void*)g,
                                   (__attribute__((address_space(3))) void*)l, 16, 0, 0);
}

// ---------------- fp32 -> bf16 conversion for 3 activations + 4 weights ----
__global__ __launch_bounds__(256)
void cvt_all(const float* __restrict__ q, const float* __restrict__ k, const float* __restrict__ v,
             const float* __restrict__ wq, const float* __restrict__ wk,
             const float* __restrict__ wv, const float* __restrict__ wo,
             u16* oq, u16* ok, u16* ov, u16* owq, u16* owk, u16* owv, u16* owo){
  const int XN4 = (NB*NS*NSTATE)/4;   // 2097152
  const int WN4 = (NSTATE*NSTATE)/4;  // 262144
  int gid = blockIdx.x * 256 + threadIdx.x;
  const float* src; u16* dst; int idx;
  if (gid < XN4)          { src = q; dst = oq; idx = gid; }
  else if (gid < 2*XN4)   { src = k; dst = ok; idx = gid - XN4; }
  else if (gid < 3*XN4)   { src = v; dst = ov; idx = gid - 2*XN4; }
  else {
    int g = gid - 3*XN4;
    int wsel = g >> 18;       // / WN4
    idx = g & (WN4 - 1);
    src = (wsel==0)?wq:(wsel==1)?wk:(wsel==2)?wv:wo;
    dst = (wsel==0)?owq:(wsel==1)?owk:(wsel==2)?owv:owo;
  }
  float4 val = ((const float4*)src)[idx];
  ushort4 r;
  r.x = f2bf(val.x); r.y = f2bf(val.y); r.z = f2bf(val.z); r.w = f2bf(val.w);
  ((ushort4*)dst)[idx] = r;
}

// ---------------- GEMM: C[m,n] = sum_k A[m,k] * Bt[n,k]  (M=8192,N=1024,K=1024)
// MODE 0: bf16 out, row-major [M][N]          (V projection)
// MODE 1: qk_scale + RoPE, bf16 out [B,H,S,D] (Q/K projection)
// MODE 2: fp32 out, row-major [M][N]          (final Wo projection)
template<int MODE>
__global__ __launch_bounds__(256)
void gemm_bt(const u16* __restrict__ A, const u16* __restrict__ Bt, void* __restrict__ outp){
  __shared__ __align__(16) u16 As[128*64];
  __shared__ __align__(16) u16 Bs[128*64];
  const int tid = threadIdx.x;
  const int lane = tid & 63, w = tid >> 6;
  const int wr = w >> 1, wc = w & 1;
  const int l15 = lane & 15, lhi = lane >> 4;
  const int brow = blockIdx.y * 128;
  const int bcol = blockIdx.x * 128;
  const int K = NSTATE;
  f32x4 acc[4][4] = {};

  for (int kt = 0; kt < K; kt += 64){
    #pragma unroll
    for (int it = 0; it < 4; ++it){           // stage A tile 128x64
      int flat = it*4096 + tid*16;
      int row = flat >> 7, colb = flat & 127;
      gld_lds16(A + (size_t)(brow+row)*K + kt + (colb>>1), As + (flat>>1));
    }
    #pragma unroll
    for (int it = 0; it < 4; ++it){           // stage B tile 128x64
      int flat = it*4096 + tid*16;
      int row = flat >> 7, colb = flat & 127;
      gld_lds16(Bt + (size_t)(bcol+row)*K + kt + (colb>>1), Bs + (flat>>1));
    }
    __syncthreads();
    #pragma unroll
    for (int ks = 0; ks < 2; ++ks){
      short8 av[4], bv[4];
      #pragma unroll
      for (int i = 0; i < 4; ++i)
        av[i] = *(const short8*)&As[(wr*64 + i*16 + l15)*64 + ks*32 + lhi*8];
      #pragma unroll
      for (int j = 0; j < 4; ++j)
        bv[j] = *(const short8*)&Bs[(wc*64 + j*16 + l15)*64 + ks*32 + lhi*8];
      #pragma unroll
      for (int i = 0; i < 4; ++i)
        #pragma unroll
        for (int j = 0; j < 4; ++j)
          acc[i][j] = mfma16x16(av[i], bv[j], acc[i][j]);
    }
    __syncthreads();
  }

  if (MODE == 0){
    u16* out = (u16*)outp;
    #pragma unroll
    for (int i = 0; i < 4; ++i)
      #pragma unroll
      for (int reg = 0; reg < 4; ++reg){
        int m = brow + wr*64 + i*16 + lhi*4 + reg;
        u16* orow = out + (size_t)m*NSTATE + bcol + wc*64;
        #pragma unroll
        for (int j = 0; j < 4; ++j)
          orow[j*16 + l15] = f2bf(acc[i][j][reg]);
      }
  } else if (MODE == 2){
    float* out = (float*)outp;
    #pragma unroll
    for (int i = 0; i < 4; ++i)
      #pragma unroll
      for (int reg = 0; reg < 4; ++reg){
        int m = brow + wr*64 + i*16 + lhi*4 + reg;
        float* orow = out + (size_t)m*NSTATE + bcol + wc*64;
        #pragma unroll
        for (int j = 0; j < 4; ++j)
          orow[j*16 + l15] = acc[i][j][reg];
      }
  } else {
    // MODE 1: scale (incl. sqrt(log2e) for exp2 softmax) + RoPE, write [B,H,S,D]
    u16* out = (u16*)outp;
    const float qk_scale = 0.4246609f;   // (1/sqrt(64))^0.5 * sqrt(log2(e))
    const int head = (bcol + wc*64) >> 6;          // wave covers exactly one head (64 cols)
    const float invf = __powf(10000.0f, -(float)l15 * (1.0f/16.0f));
    #pragma unroll
    for (int i = 0; i < 4; ++i){
      #pragma unroll
      for (int reg = 0; reg < 4; ++reg){
        int m = brow + wr*64 + i*16 + lhi*4 + reg;
        int b = m >> 11, s = m & (NS-1);
        float sn, cs;
        __sincosf((float)s * invf, &sn, &cs);
        float x0 = acc[i][0][reg]*qk_scale;   // d = l15      (first rope half)
        float x1 = acc[i][1][reg]*qk_scale;   // d = 16+l15   (second rope half)
        u16* orow = out + ((size_t)(b*NH + head)*NS + s)*ND;
        orow[ 0 + l15] = f2bf(x0*cs - x1*sn);
        orow[16 + l15] = f2bf(x1*cs + x0*sn);
        orow[32 + l15] = f2bf(acc[i][2][reg]*qk_scale);
        orow[48 + l15] = f2bf(acc[i][3][reg]*qk_scale);
      }
    }
  }
}

// ---------------- V [B,S,H,D] -> Vt [B,H,D,S] ----------------
__global__ __launch_bounds__(256)
void transpose_v(const u16* __restrict__ Vsd, u16* __restrict__ Vt){
  __shared__ u16 tile[64][65];
  const int bh = blockIdx.y, b = bh >> 4, h = bh & 15;
  const int s0 = blockIdx.x * 64;
  const int tid = threadIdx.x;
  #pragma unroll
  for (int p = 0; p < 2; ++p){
    int r = p*32 + (tid>>3);
    int c = (tid&7)*8;
    const u16* g = Vsd + ((size_t)((b*NS + s0 + r)*NH + h))*ND + c;
    ushort4 v0 = *(const ushort4*)g;
    ushort4 v1 = *(const ushort4*)(g+4);
    tile[r][c+0]=v0.x; tile[r][c+1]=v0.y; tile[r][c+2]=v0.z; tile[r][c+3]=v0.w;
    tile[r][c+4]=v1.x; tile[r][c+5]=v1.y; tile[r][c+6]=v1.z; tile[r][c+7]=v1.w;
  }
  __syncthreads();
  #pragma unroll
  for (int p = 0; p < 2; ++p){
    int d  = p*32 + (tid>>3);
    int sc = (tid&7)*8;
    union { u16 u[8]; uint4 v; } o;
    #pragma unroll
    for (int i = 0; i < 8; ++i) o.u[i] = tile[sc+i][d];
    *(uint4*)(Vt + ((size_t)(bh*ND + d))*NS + s0 + sc) = o.v;
  }
}

// ---------------- causal flash attention -----------------------------------
// grid (16, B*H), 4 waves/block, complementary chunk pairing (waves 0,1 work
// chunk blockIdx.x, waves 2,3 chunk 31-blockIdx.x).
// Latency structure: K register double-buffer (prefetch kv+64 issued right
// after QK consumes current buffer), V loads issued at iteration top (land
// under QK+softmax), exp2-domain softmax (scale folded in projection).
__global__ __launch_bounds__(256)
void flash_attn(const u16* __restrict__ Q, const u16* __restrict__ Kh,
                const u16* __restrict__ Vt, u16* __restrict__ O){
  __shared__ __align__(16) u16 Plds[4][32*64];
  const int bh = blockIdx.y;
  const int tid = threadIdx.x;
  const int w = tid >> 6, lane = tid & 63;
  const int l15 = lane & 15, lhi = lane >> 4;
  const int chunk = (w < 2) ? blockIdx.x : (31 - blockIdx.x);
  const int qw = chunk*64 + (w & 1)*32;
  const u16* Qb = Q  + (size_t)bh*NS*ND;
  const u16* Kb = Kh + (size_t)bh*NS*ND;
  const u16* Vb = Vt + (size_t)bh*ND*NS;
  u16* Pl = &Plds[w][0];

  short8 qf[2][2];
  #pragma unroll
  for (int rf = 0; rf < 2; ++rf)
    #pragma unroll
    for (int ks = 0; ks < 2; ++ks)
      qf[rf][ks] = *(const short8*)&Qb[(size_t)(qw + rf*16 + l15)*ND + ks*32 + lhi*8];

  f32x4 oacc[2][4] = {};
  float mrun[2] = {-3.0e38f, -3.0e38f};
  float lrun[2] = {0.f, 0.f};
  const int kend = qw + 32;

  short8 kA[8], kB[8];
  #pragma unroll
  for (int ks = 0; ks < 2; ++ks)
    #pragma unroll
    for (int cf = 0; cf < 4; ++cf)
      kA[ks*4+cf] = *(const short8*)&Kb[(size_t)(cf*16 + l15)*ND + ks*32 + lhi*8];

  auto body = [&](int kv0, short8 (&kf)[8], short8 (&kn)[8], bool pre){
    // ---- V loads for THIS iteration (consumed at the end; land under QK+softmax)
    short8 vf[8];
    #pragma unroll
    for (int ks = 0; ks < 2; ++ks)
      #pragma unroll
      for (int df = 0; df < 4; ++df)
        vf[ks*4+df] = *(const short8*)&Vb[(size_t)(df*16 + l15)*NS + kv0 + ks*32 + lhi*8];
    // ---- S^T = K . Q^T : rows=k (lhi*4+reg), cols=q (l15) ----
    f32x4 st[2][4] = {};
    #pragma unroll
    for (int ks = 0; ks < 2; ++ks)
      #pragma unroll
      for (int rf = 0; rf < 2; ++rf)
        #pragma unroll
        for (int cf = 0; cf < 4; ++cf)
          st[rf][cf] = mfma16x16(kf[ks*4+cf], qf[rf][ks], st[rf][cf]);
    // ---- prefetch K for NEXT iteration (lands under softmax + PV) ----
    if (pre){
      #pragma unroll
      for (int ks = 0; ks < 2; ++ks)
        #pragma unroll
        for (int cf = 0; cf < 4; ++cf)
          kn[ks*4+cf] = *(const short8*)&Kb[(size_t)(kv0 + 64 + cf*16 + l15)*ND + ks*32 + lhi*8];
    }
    // ---- causal mask: element (k = kv0+cf*16+lhi*4+reg, q = qw+rf*16+l15) ----
    if (kv0 + 63 > qw){
      #pragma unroll
      for (int rf = 0; rf < 2; ++rf){
        int qq = qw + rf*16 + l15;
        #pragma unroll
        for (int cf = 0; cf < 4; ++cf){
          int kb = kv0 + cf*16 + lhi*4;
          #pragma unroll
          for (int reg = 0; reg < 4; ++reg)
            if (kb + reg > qq) st[rf][cf][reg] = -3.0e30f;
        }
      }
    }
    // ---- per-q-row max: in-lane tree + shfl_xor(16,32) ----
    float pmax[2];
    #pragma unroll
    for (int rf = 0; rf < 2; ++rf){
      float c4[4];
      #pragma unroll
      for (int cf = 0; cf < 4; ++cf)
        c4[cf] = fmaxf(fmaxf(st[rf][cf][0], st[rf][cf][1]),
                       fmaxf(st[rf][cf][2], st[rf][cf][3]));
      float t = fmaxf(fmaxf(c4[0], c4[1]), fmaxf(c4[2], c4[3]));
      t = fmaxf(t, __shfl_xor(t, 16));
      t = fmaxf(t, __shfl_xor(t, 32));
      pmax[rf] = t;
    }
    // ---- defer-max (T13): rescale only when max grows by > 8 (log2 units) ----
    bool need = (pmax[0] > mrun[0] + 8.f) || (pmax[1] > mrun[1] + 8.f);
    if (__any(need)){
      #pragma unroll
      for (int rf = 0; rf < 2; ++rf){
        float mn = fmaxf(mrun[rf], pmax[rf]);
        float a  = EXP2(mrun[rf] - mn);
        mrun[rf] = mn;
        lrun[rf] *= a;
        #pragma unroll
        for (int reg = 0; reg < 4; ++reg){
          float aT = __shfl(a, lhi*4 + reg, 64);   // alpha for q-row lhi*4+reg
          #pragma unroll
          for (int df = 0; df < 4; ++df)
            oacc[rf][df][reg] *= aT;
        }
      }
    }
    // ---- P = exp2(S - m), row-sum, pack & store to LDS ----
    #pragma unroll
    for (int rf = 0; rf < 2; ++rf){
      #pragma unroll
      for (int cf = 0; cf < 4; ++cf)
        #pragma unroll
        for (int reg = 0; reg < 4; ++reg)
          st[rf][cf][reg] = EXP2(st[rf][cf][reg] - mrun[rf]);
      float s4[4];
      #pragma unroll
      for (int cf = 0; cf < 4; ++cf)
        s4[cf] = (st[rf][cf][0] + st[rf][cf][1]) + (st[rf][cf][2] + st[rf][cf][3]);
      float rs = (s4[0] + s4[1]) + (s4[2] + s4[3]);
      rs += __shfl_xor(rs, 16);
      rs += __shfl_xor(rs, 32);
      lrun[rf] += rs;
      int row = rf*16 + l15;
      #pragma unroll
      for (int cf = 0; cf < 4; ++cf){
        uint2 pk;
        pk.x = cvtpk(st[rf][cf][0], st[rf][cf][1]);
        pk.y = cvtpk(st[rf][cf][2], st[rf][cf][3]);
        int bo = ((row<<7) + ((cf*16 + lhi*4)<<1)) ^ ((row&7)<<4);
        *(uint2*)((char*)Pl + bo) = pk;
      }
    }
    // ---- O += P . V ----
    #pragma unroll
    for (int ks = 0; ks < 2; ++ks){
      short8 pf[2];
      #pragma unroll
      for (int rf = 0; rf < 2; ++rf){
        int row = rf*16 + l15;
        int bo = ((row<<7) + ((ks*32 + lhi*8)<<1)) ^ ((row&7)<<4);
        pf[rf] = *(const short8*)((const char*)Pl + bo);
      }
      #pragma unroll
      for (int rf = 0; rf < 2; ++rf)
        #pragma unroll
        for (int df = 0; df < 4; ++df)
          oacc[rf][df] = mfma16x16(pf[rf], vf[ks*4+df], oacc[rf][df]);
    }
  };

  int kv = 0;
  while (true){
    bool p1 = (kv + 64 < kend);
    body(kv, kA, kB, p1);
    kv += 64; if (!p1) break;
    bool p2 = (kv + 64 < kend);
    body(kv, kB, kA, p2);
    kv += 64; if (!p2) break;
  }

  // ---- epilogue: O/l -> [B,S,H*D] bf16 ----
  const int b = bh >> 4, h = bh & 15;
  #pragma unroll
  for (int rf = 0; rf < 2; ++rf){
    float inv = 1.0f / lrun[rf];
    #pragma unroll
    for (int reg = 0; reg < 4; ++reg){
      float invT = __shfl(inv, lhi*4 + reg, 64);
      int qrow = qw + rf*16 + lhi*4 + reg;
      u16* orow = O + ((size_t)(b*NS + qrow))*NSTATE + h*ND;
      #pragma unroll
      for (int df = 0; df < 4; ++df)
        orow[df*16 + l15] = f2bf(oacc[rf][df][reg] * invT);
    }
  }
}

// ---------------------------------------------------------------------------
extern "C" void kernel_launch(void* const* d_in, const int* in_sizes, int n_in,
                              void* d_out, int out_size, void* d_ws, size_t ws_size,
                              hipStream_t stream){
  const float* q_src = (const float*)d_in[0];
  const float* k_src = (const float*)d_in[1];
  const float* v_src = (const float*)d_in[2];
  // d_in[3] = position_mask (causal, statically known) — unused
  const float* Wq = (const float*)d_in[4];
  const float* Wk = (const float*)d_in[5];
  const float* Wv = (const float*)d_in[6];
  const float* Wo = (const float*)d_in[7];

  char* ws = (char*)d_ws;
  const size_t MB = 1u << 20;
  if (ws_size < 104*MB) return;   // need 104 MB of scratch

  u16* xq   = (u16*)(ws +  0*MB);   // 16 MB  (bf16 q_src)   -> reused as Vt
  u16* xk   = (u16*)(ws + 16*MB);   // 16 MB  (bf16 k_src)   -> reused as attn out
  u16* xv   = (u16*)(ws + 32*MB);   // 16 MB  (bf16 v_src)
  u16* wq16 = (u16*)(ws + 48*MB);   //  2 MB
  u16* wk16 = (u16*)(ws + 50*MB);
  u16* wv16 = (u16*)(ws + 52*MB);
  u16* wo16 = (u16*)(ws + 54*MB);
  u16* Qh   = (u16*)(ws + 56*MB);   // 16 MB  [B,H,S,D]
  u16* Kk   = (u16*)(ws + 72*MB);   // 16 MB  [B,H,S,D]
  u16* Vsd  = (u16*)(ws + 88*MB);   // 16 MB  [B,S,H,D]
  u16* Vt   = xq;                   // [B,H,D,S]  (xq dead after Q gemm)
  u16* Oat  = xk;                   // [B,S,H*D]  (xk dead after K gemm)

  cvt_all<<<dim3(28672), dim3(256), 0, stream>>>(q_src, k_src, v_src, Wq, Wk, Wv, Wo,
                                                 xq, xk, xv, wq16, wk16, wv16, wo16);
  gemm_bt<1><<<dim3(8,64), dim3(256), 0, stream>>>(xq, wq16, (void*)Qh);
  gemm_bt<1><<<dim3(8,64), dim3(256), 0, stream>>>(xk, wk16, (void*)Kk);
  gemm_bt<0><<<dim3(8,64), dim3(256), 0, stream>>>(xv, wv16, (void*)Vsd);
  transpose_v<<<dim3(32,64), dim3(256), 0, stream>>>(Vsd, Vt);
  flash_attn<<<dim3(16,64), dim3(256), 0, stream>>>(Qh, Kk, Vt, Oat);
  gemm_bt<2><<<dim3(8,64), dim3(256), 0, stream>>>(Oat, wo16, d_out);
}

// Round 4
// 270.751 us; speedup vs baseline: 1.4616x; 1.1306x over previous
//
#include <hip/hip_runtime.h>

typedef unsigned short u16;
typedef unsigned int u32;
typedef short short8 __attribute__((ext_vector_type(8)));
typedef float f32x4 __attribute__((ext_vector_type(4)));

#define NB 4
#define NS 2048
#define NSTATE 1024
#define NH 16
#define ND 64
#define NM (NB*NS)   // 8192 rows

#if __has_builtin(__builtin_amdgcn_exp2f)
#define EXP2(x) __builtin_amdgcn_exp2f(x)
#else
#define EXP2(x) __expf((x) * 0.6931471805599453f)
#endif

__device__ __forceinline__ u16 f2bf(float f){
  union { float fv; unsigned uv; } x; x.fv = f;
  unsigned r = x.uv + 0x7fffu + ((x.uv >> 16) & 1u);
  return (u16)(r >> 16);
}

__device__ __forceinline__ u32 cvtpk(float lo, float hi){
  u32 r;
  asm("v_cvt_pk_bf16_f32 %0, %1, %2" : "=v"(r) : "v"(lo), "v"(hi));
  return r;
}

__device__ __forceinline__ f32x4 mfma16x16(short8 a, short8 b, f32x4 c){
  return __builtin_amdgcn_mfma_f32_16x16x32_bf16(a, b, c, 0, 0, 0);
}

__device__ __forceinline__ void gld_lds16(const u16* g, u16* l){
  __builtin_amdgcn_global_load_lds((const __attribute__((address_space(1))) void*)g,
                                   (__attribute__((address_space(3))) void*)l, 16, 0, 0);
}

// ---------------- fp32 -> bf16 conversion for 3 activations + 4 weights ----
__global__ __launch_bounds__(256)
void cvt_all(const float* __restrict__ q, const float* __restrict__ k, const float* __restrict__ v,
             const float* __restrict__ wq, const float* __restrict__ wk,
             const float* __restrict__ wv, const float* __restrict__ wo,
             u16* oq, u16* ok, u16* ov, u16* owq, u16* owk, u16* owv, u16* owo){
  const int XN4 = (NB*NS*NSTATE)/4;   // 2097152
  const int WN4 = (NSTATE*NSTATE)/4;  // 262144
  int gid = blockIdx.x * 256 + threadIdx.x;
  const float* src; u16* dst; int idx;
  if (gid < XN4)          { src = q; dst = oq; idx = gid; }
  else if (gid < 2*XN4)   { src = k; dst = ok; idx = gid - XN4; }
  else if (gid < 3*XN4)   { src = v; dst = ov; idx = gid - 2*XN4; }
  else {
    int g = gid - 3*XN4;
    int wsel = g >> 18;       // / WN4
    idx = g & (WN4 - 1);
    src = (wsel==0)?wq:(wsel==1)?wk:(wsel==2)?wv:wo;
    dst = (wsel==0)?owq:(wsel==1)?owk:(wsel==2)?owv:owo;
  }
  float4 val = ((const float4*)src)[idx];
  ushort4 r;
  r.x = f2bf(val.x); r.y = f2bf(val.y); r.z = f2bf(val.z); r.w = f2bf(val.w);
  ((ushort4*)dst)[idx] = r;
}

// ---------------- merged QKV projection GEMM -------------------------------
// Output cols [0,1024)=Q(RoPE), [1024,2048)=K(RoPE), [2048,3072)=V(plain).
// A matrix selected per column block (xq/xk/xv). Wcat = wq||wk||wv rows.
// Flat grid 1536, XCD-swizzled (8 row-panels per XCD).
__global__ __launch_bounds__(256)
void gemm_qkv(const u16* __restrict__ xq, const u16* __restrict__ xk,
              const u16* __restrict__ xv, const u16* __restrict__ Wcat,
              u16* __restrict__ Qh, u16* __restrict__ Kk, u16* __restrict__ Vsd){
  __shared__ __align__(16) u16 As[128*64];
  __shared__ __align__(16) u16 Bs[128*64];
  const int gblk = blockIdx.x;
  const int wid = (gblk & 7) * 192 + (gblk >> 3);
  const int bx = wid % 24, by = wid / 24;
  const int sel = bx >> 3;                        // 0=Q 1=K 2=V
  const u16* A = (sel==0) ? xq : (sel==1) ? xk : xv;
  const int tid = threadIdx.x;
  const int lane = tid & 63, w = tid >> 6;
  const int wr = w >> 1, wc = w & 1;
  const int l15 = lane & 15, lhi = lane >> 4;
  const int brow = by * 128;
  const int bcol = bx * 128;                      // global col in [0,3072)
  const int K = NSTATE;
  f32x4 acc[4][4] = {};

  for (int kt = 0; kt < K; kt += 64){
    #pragma unroll
    for (int it = 0; it < 4; ++it){
      int flat = it*4096 + tid*16;
      int row = flat >> 7, colb = flat & 127;
      gld_lds16(A + (size_t)(brow+row)*K + kt + (colb>>1), As + (flat>>1));
    }
    #pragma unroll
    for (int it = 0; it < 4; ++it){
      int flat = it*4096 + tid*16;
      int row = flat >> 7, colb = flat & 127;
      gld_lds16(Wcat + (size_t)(bcol+row)*K + kt + (colb>>1), Bs + (flat>>1));
    }
    __syncthreads();
    #pragma unroll
    for (int ks = 0; ks < 2; ++ks){
      short8 av[4], bv[4];
      #pragma unroll
      for (int i = 0; i < 4; ++i)
        av[i] = *(const short8*)&As[(wr*64 + i*16 + l15)*64 + ks*32 + lhi*8];
      #pragma unroll
      for (int j = 0; j < 4; ++j)
        bv[j] = *(const short8*)&Bs[(wc*64 + j*16 + l15)*64 + ks*32 + lhi*8];
      #pragma unroll
      for (int i = 0; i < 4; ++i)
        #pragma unroll
        for (int j = 0; j < 4; ++j)
          acc[i][j] = mfma16x16(av[i], bv[j], acc[i][j]);
    }
    __syncthreads();
  }

  const int col0 = bcol + wc*64;                  // wave's 64-col slab (one head)
  if (sel == 2){
    // V: plain bf16 [B,S,H,D] == row m, col (col0&1023)
    u16* out = Vsd;
    int c = col0 & 1023;
    #pragma unroll
    for (int i = 0; i < 4; ++i)
      #pragma unroll
      for (int reg = 0; reg < 4; ++reg){
        int m = brow + wr*64 + i*16 + lhi*4 + reg;
        u16* orow = out + (size_t)m*NSTATE + c;
        #pragma unroll
        for (int j = 0; j < 4; ++j)
          orow[j*16 + l15] = f2bf(acc[i][j][reg]);
      }
  } else {
    // Q/K: scale (incl sqrt(log2e)) + RoPE, write [B,H,S,D]
    u16* out = sel ? Kk : Qh;
    const float qk_scale = 0.4246609f;            // (1/8)^0.5 * sqrt(log2 e)
    const int head = (col0 & 1023) >> 6;
    const float invf = __powf(10000.0f, -(float)l15 * (1.0f/16.0f));
    #pragma unroll
    for (int i = 0; i < 4; ++i){
      #pragma unroll
      for (int reg = 0; reg < 4; ++reg){
        int m = brow + wr*64 + i*16 + lhi*4 + reg;
        int b = m >> 11, s = m & (NS-1);
        float sn, cs;
        __sincosf((float)s * invf, &sn, &cs);
        float x0 = acc[i][0][reg]*qk_scale;
        float x1 = acc[i][1][reg]*qk_scale;
        u16* orow = out + ((size_t)(b*NH + head)*NS + s)*ND;
        orow[ 0 + l15] = f2bf(x0*cs - x1*sn);
        orow[16 + l15] = f2bf(x1*cs + x0*sn);
        orow[32 + l15] = f2bf(acc[i][2][reg]*qk_scale);
        orow[48 + l15] = f2bf(acc[i][3][reg]*qk_scale);
      }
    }
  }
}

// ---------------- Wo GEMM: fp32 out, flat grid 512, XCD-swizzled -----------
__global__ __launch_bounds__(256)
void gemm_wo(const u16* __restrict__ A, const u16* __restrict__ Bt, float* __restrict__ out){
  __shared__ __align__(16) u16 As[128*64];
  __shared__ __align__(16) u16 Bs[128*64];
  const int gblk = blockIdx.x;
  const int wid = (gblk & 7) * 64 + (gblk >> 3);
  const int bx = wid & 7, by = wid >> 3;
  const int tid = threadIdx.x;
  const int lane = tid & 63, w = tid >> 6;
  const int wr = w >> 1, wc = w & 1;
  const int l15 = lane & 15, lhi = lane >> 4;
  const int brow = by * 128;
  const int bcol = bx * 128;
  const int K = NSTATE;
  f32x4 acc[4][4] = {};

  for (int kt = 0; kt < K; kt += 64){
    #pragma unroll
    for (int it = 0; it < 4; ++it){
      int flat = it*4096 + tid*16;
      int row = flat >> 7, colb = flat & 127;
      gld_lds16(A + (size_t)(brow+row)*K + kt + (colb>>1), As + (flat>>1));
    }
    #pragma unroll
    for (int it = 0; it < 4; ++it){
      int flat = it*4096 + tid*16;
      int row = flat >> 7, colb = flat & 127;
      gld_lds16(Bt + (size_t)(bcol+row)*K + kt + (colb>>1), Bs + (flat>>1));
    }
    __syncthreads();
    #pragma unroll
    for (int ks = 0; ks < 2; ++ks){
      short8 av[4], bv[4];
      #pragma unroll
      for (int i = 0; i < 4; ++i)
        av[i] = *(const short8*)&As[(wr*64 + i*16 + l15)*64 + ks*32 + lhi*8];
      #pragma unroll
      for (int j = 0; j < 4; ++j)
        bv[j] = *(const short8*)&Bs[(wc*64 + j*16 + l15)*64 + ks*32 + lhi*8];
      #pragma unroll
      for (int i = 0; i < 4; ++i)
        #pragma unroll
        for (int j = 0; j < 4; ++j)
          acc[i][j] = mfma16x16(av[i], bv[j], acc[i][j]);
    }
    __syncthreads();
  }
  #pragma unroll
  for (int i = 0; i < 4; ++i)
    #pragma unroll
    for (int reg = 0; reg < 4; ++reg){
      int m = brow + wr*64 + i*16 + lhi*4 + reg;
      float* orow = out + (size_t)m*NSTATE + bcol + wc*64;
      #pragma unroll
      for (int j = 0; j < 4; ++j)
        orow[j*16 + l15] = acc[i][j][reg];
    }
}

// ---------------- V [B,S,H,D] -> Vt [B,H,D,S] ----------------
__global__ __launch_bounds__(256)
void transpose_v(const u16* __restrict__ Vsd, u16* __restrict__ Vt){
  __shared__ u16 tile[64][65];
  const int bh = blockIdx.y, b = bh >> 4, h = bh & 15;
  const int s0 = blockIdx.x * 64;
  const int tid = threadIdx.x;
  #pragma unroll
  for (int p = 0; p < 2; ++p){
    int r = p*32 + (tid>>3);
    int c = (tid&7)*8;
    const u16* g = Vsd + ((size_t)((b*NS + s0 + r)*NH + h))*ND + c;
    ushort4 v0 = *(const ushort4*)g;
    ushort4 v1 = *(const ushort4*)(g+4);
    tile[r][c+0]=v0.x; tile[r][c+1]=v0.y; tile[r][c+2]=v0.z; tile[r][c+3]=v0.w;
    tile[r][c+4]=v1.x; tile[r][c+5]=v1.y; tile[r][c+6]=v1.z; tile[r][c+7]=v1.w;
  }
  __syncthreads();
  #pragma unroll
  for (int p = 0; p < 2; ++p){
    int d  = p*32 + (tid>>3);
    int sc = (tid&7)*8;
    union { u16 u[8]; uint4 v; } o;
    #pragma unroll
    for (int i = 0; i < 8; ++i) o.u[i] = tile[sc+i][d];
    *(uint4*)(Vt + ((size_t)(bh*ND + d))*NS + s0 + sc) = o.v;
  }
}

// ---------------- causal flash attention -----------------------------------
// 1-wave (64-thread) blocks, flat grid 2048, XCD-swizzled so each XCD owns
// 8 consecutive bh (KV footprint 4 MB = one L2). Each wave processes the
// complementary q-tile pair (t, 63-t) sequentially -> exactly 33 kv-iters
// per wave, no intra-block drain. K register dbuf + V issue-early + exp2
// softmax + defer-max + setprio around MFMA clusters.
__global__ __launch_bounds__(64, 2)
void flash_attn(const u16* __restrict__ Q, const u16* __restrict__ Kh,
                const u16* __restrict__ Vt, u16* __restrict__ O){
  __shared__ __align__(16) u16 Pl[32*64];
  const int gblk = blockIdx.x;
  const int wid = (gblk & 7) * 256 + (gblk >> 3);
  const int bh = wid >> 5, pair = wid & 31;
  const int lane = threadIdx.x;
  const int l15 = lane & 15, lhi = lane >> 4;
  const u16* Qb = Q  + (size_t)bh*NS*ND;
  const u16* Kb = Kh + (size_t)bh*NS*ND;
  const u16* Vb = Vt + (size_t)bh*ND*NS;
  const int b = bh >> 4, h = bh & 15;

  for (int tsel = 0; tsel < 2; ++tsel){
    const int qw = (tsel ? (63 - pair) : pair) * 32;

    short8 qf[2][2];
    #pragma unroll
    for (int rf = 0; rf < 2; ++rf)
      #pragma unroll
      for (int ks = 0; ks < 2; ++ks)
        qf[rf][ks] = *(const short8*)&Qb[(size_t)(qw + rf*16 + l15)*ND + ks*32 + lhi*8];

    f32x4 oacc[2][4] = {};
    float mrun[2] = {-3.0e38f, -3.0e38f};
    float lrun[2] = {0.f, 0.f};
    const int kend = qw + 32;

    short8 kA[8], kB[8];
    #pragma unroll
    for (int ks = 0; ks < 2; ++ks)
      #pragma unroll
      for (int cf = 0; cf < 4; ++cf)
        kA[ks*4+cf] = *(const short8*)&Kb[(size_t)(cf*16 + l15)*ND + ks*32 + lhi*8];

    auto body = [&](int kv0, short8 (&kf)[8], short8 (&kn)[8], bool pre){
      // V loads for THIS iteration (consumed at the end; land under QK+softmax)
      short8 vf[8];
      #pragma unroll
      for (int ks = 0; ks < 2; ++ks)
        #pragma unroll
        for (int df = 0; df < 4; ++df)
          vf[ks*4+df] = *(const short8*)&Vb[(size_t)(df*16 + l15)*NS + kv0 + ks*32 + lhi*8];
      // S^T = K . Q^T : rows=k (lhi*4+reg), cols=q (l15)
      f32x4 st[2][4] = {};
      __builtin_amdgcn_s_setprio(1);
      #pragma unroll
      for (int ks = 0; ks < 2; ++ks)
        #pragma unroll
        for (int rf = 0; rf < 2; ++rf)
          #pragma unroll
          for (int cf = 0; cf < 4; ++cf)
            st[rf][cf] = mfma16x16(kf[ks*4+cf], qf[rf][ks], st[rf][cf]);
      __builtin_amdgcn_s_setprio(0);
      // prefetch K for NEXT iteration (lands under softmax + PV)
      if (pre){
        #pragma unroll
        for (int ks = 0; ks < 2; ++ks)
          #pragma unroll
          for (int cf = 0; cf < 4; ++cf)
            kn[ks*4+cf] = *(const short8*)&Kb[(size_t)(kv0 + 64 + cf*16 + l15)*ND + ks*32 + lhi*8];
      }
      // causal mask: element (k = kv0+cf*16+lhi*4+reg, q = qw+rf*16+l15)
      if (kv0 + 63 > qw){
        #pragma unroll
        for (int rf = 0; rf < 2; ++rf){
          int qq = qw + rf*16 + l15;
          #pragma unroll
          for (int cf = 0; cf < 4; ++cf){
            int kb = kv0 + cf*16 + lhi*4;
            #pragma unroll
            for (int reg = 0; reg < 4; ++reg)
              if (kb + reg > qq) st[rf][cf][reg] = -3.0e30f;
          }
        }
      }
      // per-q-row max: in-lane tree + shfl_xor(16,32)
      float pmax[2];
      #pragma unroll
      for (int rf = 0; rf < 2; ++rf){
        float c4[4];
        #pragma unroll
        for (int cf = 0; cf < 4; ++cf)
          c4[cf] = fmaxf(fmaxf(st[rf][cf][0], st[rf][cf][1]),
                         fmaxf(st[rf][cf][2], st[rf][cf][3]));
        float t = fmaxf(fmaxf(c4[0], c4[1]), fmaxf(c4[2], c4[3]));
        t = fmaxf(t, __shfl_xor(t, 16));
        t = fmaxf(t, __shfl_xor(t, 32));
        pmax[rf] = t;
      }
      // defer-max (T13): rescale only when max grows by > 8 (log2 units)
      bool need = (pmax[0] > mrun[0] + 8.f) || (pmax[1] > mrun[1] + 8.f);
      if (__any(need)){
        #pragma unroll
        for (int rf = 0; rf < 2; ++rf){
          float mn = fmaxf(mrun[rf], pmax[rf]);
          float a  = EXP2(mrun[rf] - mn);
          mrun[rf] = mn;
          lrun[rf] *= a;
          #pragma unroll
          for (int reg = 0; reg < 4; ++reg){
            float aT = __shfl(a, lhi*4 + reg, 64);
            #pragma unroll
            for (int df = 0; df < 4; ++df)
              oacc[rf][df][reg] *= aT;
          }
        }
      }
      // P = exp2(S - m), row-sum, pack & store to LDS
      #pragma unroll
      for (int rf = 0; rf < 2; ++rf){
        #pragma unroll
        for (int cf = 0; cf < 4; ++cf)
          #pragma unroll
          for (int reg = 0; reg < 4; ++reg)
            st[rf][cf][reg] = EXP2(st[rf][cf][reg] - mrun[rf]);
        float s4[4];
        #pragma unroll
        for (int cf = 0; cf < 4; ++cf)
          s4[cf] = (st[rf][cf][0] + st[rf][cf][1]) + (st[rf][cf][2] + st[rf][cf][3]);
        float rs = (s4[0] + s4[1]) + (s4[2] + s4[3]);
        rs += __shfl_xor(rs, 16);
        rs += __shfl_xor(rs, 32);
        lrun[rf] += rs;
        int row = rf*16 + l15;
        #pragma unroll
        for (int cf = 0; cf < 4; ++cf){
          uint2 pk;
          pk.x = cvtpk(st[rf][cf][0], st[rf][cf][1]);
          pk.y = cvtpk(st[rf][cf][2], st[rf][cf][3]);
          int bo = ((row<<7) + ((cf*16 + lhi*4)<<1)) ^ ((row&7)<<4);
          *(uint2*)((char*)Pl + bo) = pk;
        }
      }
      // O += P . V
      #pragma unroll
      for (int ks = 0; ks < 2; ++ks){
        short8 pf[2];
        #pragma unroll
        for (int rf = 0; rf < 2; ++rf){
          int row = rf*16 + l15;
          int bo = ((row<<7) + ((ks*32 + lhi*8)<<1)) ^ ((row&7)<<4);
          pf[rf] = *(const short8*)((const char*)Pl + bo);
        }
        __builtin_amdgcn_s_setprio(1);
        #pragma unroll
        for (int rf = 0; rf < 2; ++rf)
          #pragma unroll
          for (int df = 0; df < 4; ++df)
            oacc[rf][df] = mfma16x16(pf[rf], vf[ks*4+df], oacc[rf][df]);
        __builtin_amdgcn_s_setprio(0);
      }
    };

    int kv = 0;
    while (true){
      bool p1 = (kv + 64 < kend);
      body(kv, kA, kB, p1);
      kv += 64; if (!p1) break;
      bool p2 = (kv + 64 < kend);
      body(kv, kB, kA, p2);
      kv += 64; if (!p2) break;
    }

    // epilogue: O/l -> [B,S,H*D] bf16
    #pragma unroll
    for (int rf = 0; rf < 2; ++rf){
      float inv = 1.0f / lrun[rf];
      #pragma unroll
      for (int reg = 0; reg < 4; ++reg){
        float invT = __shfl(inv, lhi*4 + reg, 64);
        int qrow = qw + rf*16 + lhi*4 + reg;
        u16* orow = O + ((size_t)(b*NS + qrow))*NSTATE + h*ND;
        #pragma unroll
        for (int df = 0; df < 4; ++df)
          orow[df*16 + l15] = f2bf(oacc[rf][df][reg] * invT);
      }
    }
  }
}

// ---------------------------------------------------------------------------
extern "C" void kernel_launch(void* const* d_in, const int* in_sizes, int n_in,
                              void* d_out, int out_size, void* d_ws, size_t ws_size,
                              hipStream_t stream){
  const float* q_src = (const float*)d_in[0];
  const float* k_src = (const float*)d_in[1];
  const float* v_src = (const float*)d_in[2];
  // d_in[3] = position_mask (causal, statically known) — unused
  const float* Wq = (const float*)d_in[4];
  const float* Wk = (const float*)d_in[5];
  const float* Wv = (const float*)d_in[6];
  const float* Wo = (const float*)d_in[7];

  char* ws = (char*)d_ws;
  const size_t MB = 1u << 20;
  if (ws_size < 104*MB) return;   // need 104 MB of scratch

  u16* xq   = (u16*)(ws +  0*MB);   // 16 MB  (bf16 q_src)   -> reused as Vt
  u16* xk   = (u16*)(ws + 16*MB);   // 16 MB  (bf16 k_src)   -> reused as attn out
  u16* xv   = (u16*)(ws + 32*MB);   // 16 MB  (bf16 v_src)
  u16* wq16 = (u16*)(ws + 48*MB);   //  2 MB  } contiguous => Wcat [3072][1024]
  u16* wk16 = (u16*)(ws + 50*MB);   //  2 MB  }
  u16* wv16 = (u16*)(ws + 52*MB);   //  2 MB  }
  u16* wo16 = (u16*)(ws + 54*MB);   //  2 MB
  u16* Qh   = (u16*)(ws + 56*MB);   // 16 MB  [B,H,S,D]
  u16* Kk   = (u16*)(ws + 72*MB);   // 16 MB  [B,H,S,D]
  u16* Vsd  = (u16*)(ws + 88*MB);   // 16 MB  [B,S,H,D]
  u16* Vt   = xq;                   // [B,H,D,S]  (xq dead after QKV gemm)
  u16* Oat  = xk;                   // [B,S,H*D]  (xk dead after QKV gemm)

  cvt_all<<<dim3(28672), dim3(256), 0, stream>>>(q_src, k_src, v_src, Wq, Wk, Wv, Wo,
                                                 xq, xk, xv, wq16, wk16, wv16, wo16);
  gemm_qkv<<<dim3(1536), dim3(256), 0, stream>>>(xq, xk, xv, wq16, Qh, Kk, Vsd);
  transpose_v<<<dim3(32,64), dim3(256), 0, stream>>>(Vsd, Vt);
  flash_attn<<<dim3(2048), dim3(64), 0, stream>>>(Qh, Kk, Vt, Oat);
  gemm_wo<<<dim3(512), dim3(256), 0, stream>>>(Oat, wo16, (float*)d_out);
}